// Round 8
// baseline (300.236 us; speedup 1.0000x reference)
//
#include <hip/hip_runtime.h>
#include <hip/hip_bf16.h>

#define BN 16384
#define TT 12
#define MLP 1024
#define ZD 32
#define HD 128
#define KD 1056          // MLP+ZD
#define GN 384           // 3*H
#define WIH_LD 1060      // MLP+ZD+2*NPRED
#define NSG 4
#define DTC 1.6f
#define PLD 512          // P leading dim: [gates_zx(384) | h0(128)], biases baked in
#define SLD 40           // GEMM LDS tile row stride (bf16): 80B -> <=2-way banks
#define GRU_ROWS 16     // rows per k_gru block (256 threads, 4 waves)

typedef __attribute__((ext_vector_type(8))) short short8;
typedef __attribute__((ext_vector_type(4))) short short4_t;
typedef __attribute__((ext_vector_type(4))) float floatx4;
typedef __hip_bfloat16 bf16;

__device__ __forceinline__ float bf2f(bf16 v) { return __bfloat162float(v); }
__device__ __forceinline__ bf16 f2bf(float v) { return __float2bfloat16(v); }
__device__ __forceinline__ short bfbits(float x) {
    bf16 t = __float2bfloat16(x);
    return __builtin_bit_cast(short, t);
}
__device__ __forceinline__ float bfraw2f(unsigned short u) {
    return __uint_as_float(((unsigned int)u) << 16);
}
// rcp-based gates: saves div sequence; |err| ~1ulp of rcp, fine vs 3.4e-2 thr
__device__ __forceinline__ float sigm(float x) {
    return __builtin_amdgcn_rcpf(1.0f + __expf(-x));
}
__device__ __forceinline__ float tanh_f(float x) {
    return 1.0f - 2.0f * __builtin_amdgcn_rcpf(1.0f + __expf(2.0f * x));
}
__device__ __forceinline__ short8 pack8(floatx4 a, floatx4 b) {
    short8 v;
    v[0]=bfbits(a[0]); v[1]=bfbits(a[1]); v[2]=bfbits(a[2]); v[3]=bfbits(a[3]);
    v[4]=bfbits(b[0]); v[5]=bfbits(b[1]); v[6]=bfbits(b[2]); v[7]=bfbits(b[3]);
    return v;
}
__device__ __forceinline__ short8 ld8f(const float* q) {
    return pack8(*(const floatx4*)q, *(const floatx4*)(q + 4));
}
// barrier that waits LDS ops only — leaves global loads/stores in flight
__device__ __forceinline__ void barrier_lgkm() {
    asm volatile("s_waitcnt lgkmcnt(0)\n\ts_barrier" ::: "memory");
}

// ---------------------------------------------------------------------------
// k_gemm — unchanged from round 7 (A-reuse swizzle kept; it preserved m%8).
// ---------------------------------------------------------------------------
__global__ __launch_bounds__(512, 4) void k_gemm(
    const float* __restrict__ enc, const float* __restrict__ zz,
    const float* __restrict__ Wih, const float* __restrict__ Wdec,
    const float* __restrict__ bih, const float* __restrict__ bhh,
    const float* __restrict__ bdec,
    bf16* __restrict__ P)
{
    __shared__ __align__(16) bf16 sA[2][128 * SLD];
    __shared__ __align__(16) bf16 sB[2][128 * SLD];
    const int tid = threadIdx.x;
    const int lane = tid & 63;
    const int wav = tid >> 6;
    const int wm2 = wav >> 2;         // 0..1
    const int wn2 = wav & 3;          // 0..3
    const int c = lane & 15;
    const int quad = lane >> 4;
    const int d = blockIdx.x;         // 0..511
    const int xcd = d & 7;
    const int slot = d >> 3;          // 0..63
    const int m0 = ((slot >> 2) * 8 + xcd) * 128;
    const int n0 = (slot & 3) * 128;

    const int srow = tid >> 2;        // 0..127
    const int scq = (tid & 3) * 8;    // 0/8/16/24
    const int nn = n0 + srow;
    const float* arow = enc + (size_t)(m0 + srow) * MLP + scq;
    const float* zrow = zz + (size_t)(m0 + srow) * ZD + scq;
    const float* brow = (nn < GN) ? Wih + (size_t)nn * WIH_LD + scq
                                  : Wdec + (size_t)(nn - GN) * KD + scq;

    floatx4 pa[2][2], pb[2][2];
#pragma unroll
    for (int s0 = 0; s0 < 2; s0++) {
        const float* qa = arow + s0 * 32;
        const float* qb = brow + s0 * 32;
        pa[s0][0] = *(const floatx4*)qa; pa[s0][1] = *(const floatx4*)(qa + 4);
        pb[s0][0] = *(const floatx4*)qb; pb[s0][1] = *(const floatx4*)(qb + 4);
    }

    // per-thread output-column biases (2 cols), L2-hot scalar loads, once
    float bias[2];
#pragma unroll
    for (int j = 0; j < 2; j++) {
        const int n = n0 + wn2 * 32 + j * 16 + c;
        bias[j] = (n < GN) ? (bih[n] + (n < 256 ? bhh[n] : 0.0f)) : bdec[n - GN];
    }

    floatx4 acc[4][2];
#pragma unroll
    for (int i = 0; i < 4; i++)
#pragma unroll
        for (int j = 0; j < 2; j++) acc[i][j] = floatx4{0.f, 0.f, 0.f, 0.f};

    for (int kc = 0; kc < 33; kc++) {
        const int sl = kc & 1;
        *(short8*)&sA[sl][srow * SLD + scq] = pack8(pa[sl][0], pa[sl][1]);
        *(short8*)&sB[sl][srow * SLD + scq] = pack8(pb[sl][0], pb[sl][1]);
        if (kc + 2 < 33) {
            const int k2 = (kc + 2) * 32;
            const float* qa = (kc + 2 < 32) ? arow + k2 : zrow;
            const float* qb = brow + k2;
            pa[sl][0] = *(const floatx4*)qa; pa[sl][1] = *(const floatx4*)(qa + 4);
            pb[sl][0] = *(const floatx4*)qb; pb[sl][1] = *(const floatx4*)(qb + 4);
        }
        barrier_lgkm();
        short8 a[4], b[2];
#pragma unroll
        for (int i = 0; i < 4; i++)
            a[i] = *(const short8*)&sA[sl][(wm2 * 64 + i * 16 + c) * SLD + quad * 8];
#pragma unroll
        for (int j = 0; j < 2; j++)
            b[j] = *(const short8*)&sB[sl][(wn2 * 32 + j * 16 + c) * SLD + quad * 8];
#pragma unroll
        for (int i = 0; i < 4; i++)
#pragma unroll
            for (int j = 0; j < 2; j++)
                acc[i][j] = __builtin_amdgcn_mfma_f32_16x16x32_bf16(
                    a[i], b[j], acc[i][j], 0, 0, 0);
    }
#pragma unroll
    for (int i = 0; i < 4; i++)
#pragma unroll
        for (int j = 0; j < 2; j++)
#pragma unroll
            for (int r = 0; r < 4; r++)
                P[(size_t)(m0 + wm2 * 64 + i * 16 + quad * 4 + r) * PLD
                  + n0 + wn2 * 32 + j * 16 + c] = f2bf(acc[i][j][r] + bias[j]);
}

// ---------------------------------------------------------------------------
// GRU kernel, round-7 structure, now template<NSTEPS> for the SLOPE PROBE.
// k_gru<12> = real output. k_gru<2> = probe writing to ws scratch: identical
// prologue (ext staging still covers all TT steps), identical step code,
// only the T-loop trip count differs. dur12 and dur2 give:
//   per-step = (dur12 - dur2)/10 ; prologue = dur2 - 2*per-step.
// This is the ablation the last 5 theory rounds lacked (model says ~5 us
// for the T-loop; measured 81 — the split decides the next restructure).
// __launch_bounds__ 2nd arg MUST stay <=2 (round-1: (256,4) spilled Whh).
// ---------------------------------------------------------------------------
struct SMem {
    bf16 pst[GRU_ROWS][520];    // staged P-tile (+8 pad)
    bf16 h[2][GRU_ROWS][136];   // 272B rows: 2-way banks (free) for b128 reads
    bf16 ext[TT][GRU_ROWS][4];  // per-step (a0,a1,sg0,sg1)
    float sgf[NSG][GRU_ROWS][2];
    float a0[GRU_ROWS][2];
};

template<int NSTEPS>
__global__ __launch_bounds__(256, 2) void k_gru(
    const float* __restrict__ lst, const float* __restrict__ lpos,
    const float* __restrict__ sg, const float* __restrict__ fut,
    const int* __restrict__ updp,
    const float* __restrict__ Wtv, const float* __restrict__ btv,
    const float* __restrict__ Wih,
    const float* __restrict__ Whh, const float* __restrict__ bhh,
    const float* __restrict__ Wmu, const float* __restrict__ bmu,
    const float* __restrict__ Wstd, const float* __restrict__ bstd,
    const float* __restrict__ Wsg, const float* __restrict__ bsg,
    const bf16* __restrict__ P, float* __restrict__ out)
{
    __shared__ __align__(16) SMem s;
    const int tid = threadIdx.x;
    const int lane = tid & 63;
    const int wav = tid >> 6;         // 0..3
    const int c = lane & 15;
    const int quad = lane >> 4;
    // XCD-affinity block swizzle (bijective; floor(b/8) === d mod 8)
    const int d = blockIdx.x;
    const int b = 8 * (d & 7) + 64 * (d >> 6) + ((d >> 3) & 7);
    const int rows0 = b * GRU_ROWS;
    const int jb = wav * 32;
    const size_t TB2 = (size_t)TT * BN * 2;

    // ---------- stage P-tile: 4 coalesced 16B loads/thread ----------
#pragma unroll
    for (int it = 0; it < 4; it++) {
        const int idx = it * 256 + tid;      // 0..1023 chunks of 8 bf16
        const int row = idx >> 6;            // 64 chunks per 512-col row
        const int col8 = idx & 63;
        *(short8*)&s.pst[row][col8 * 8] =
            *(const short8*)&P[(size_t)(rows0 + row) * PLD + col8 * 8];
    }

    // ---------- prologue misc ----------
    if (tid < GRU_ROWS) {
        const int row = rows0 + tid;
        for (int pp = 0; pp < 2; pp++) {
            float sum = btv[pp];
            for (int f = 0; f < 6; f++)
                sum += lst[(size_t)row * 6 + f] * Wtv[pp * 6 + f];
            s.a0[tid][pp] = sum;
        }
        float px = lpos[(size_t)row * 2];
        float py = lpos[(size_t)row * 2 + 1];
        float prevx = 0.f, prevy = 0.f;
        for (int j = 0; j < NSG; j++) {
            float rx = (sg[((size_t)row * NSG + j) * 2] - px) * 0.01f;
            float ry = (sg[((size_t)row * NSG + j) * 2 + 1] - py) * 0.01f;
            float vx = (rx - prevx) * (1.0f / DTC), vy = (ry - prevy) * (1.0f / DTC);
            prevx = rx; prevy = ry;
            float st4[4] = {rx, ry, vx, vy};
            for (int pp = 0; pp < 2; pp++) {
                float sum = bsg[pp];
                for (int f = 0; f < 4; f++) sum += st4[f] * Wsg[pp * 4 + f];
                s.sgf[j][tid][pp] = sum;
            }
        }
    }
    int upd[4];
#pragma unroll
    for (int i = 0; i < 4; i++) upd[i] = updp[i];

    // W_hh fragments (step-invariant, register-resident; ~96 VGPR)
    short8 Wb[2][3][4];
    short8 Wb4[2][2];
    float Wa2[2][2], Ws2[2][2], bhh2[2];
#pragma unroll
    for (int jt2 = 0; jt2 < 2; jt2++) {
#pragma unroll
        for (int g = 0; g < 3; g++) {
            const int n = g * 128 + jb + jt2 * 16 + c;
#pragma unroll
            for (int kc = 0; kc < 4; kc++)
                Wb[jt2][g][kc] = ld8f(Whh + (size_t)n * HD + kc * 32 + quad * 8);
            if (g < 2) {
                short8 v = {0, 0, 0, 0, 0, 0, 0, 0};
                if (quad == 0) {
                    const float* q = Wih + (size_t)n * WIH_LD + KD;
                    v[0] = bfbits(q[0]); v[1] = bfbits(q[1]);
                    v[2] = bfbits(q[2]); v[3] = bfbits(q[3]);
                }
                Wb4[jt2][g] = v;
            }
        }
        const int n2 = 256 + jb + jt2 * 16 + c;
        const float* q2 = Wih + (size_t)n2 * WIH_LD + KD;
        Wa2[jt2][0] = q2[0]; Wa2[jt2][1] = q2[1];
        Ws2[jt2][0] = q2[2]; Ws2[jt2][1] = q2[3];
        bhh2[jt2] = bhh[n2];
    }

    // heads B-fragments: muw as bf16, B-col = sel (c<4), k = kc*32+quad*8.
    short8 mwb[4];
    float hbias = 0.0f;
#pragma unroll
    for (int kc = 0; kc < 4; kc++) {
        short8 v = {0, 0, 0, 0, 0, 0, 0, 0};
        if (c < 4) {
            const float* q = (c < 2 ? Wmu + (size_t)c * HD
                                    : Wstd + (size_t)(c - 2) * HD)
                             + kc * 32 + quad * 8;
            v = ld8f(q);
        }
        mwb[kc] = v;
    }
    if (c < 4) hbias = (c < 2) ? bmu[c] : bstd[c - 2];

    __syncthreads();   // pst + sgf/a0 ready

    // ---------- P1: consume staged P (biases baked); h0 -> buf 1; ext ----------
    floatx4 gzx[2][3];
#pragma unroll
    for (int jt2 = 0; jt2 < 2; jt2++) {
#pragma unroll
        for (int g = 0; g < 3; g++) {
            const int n = g * 128 + jb + jt2 * 16 + c;
            floatx4 v;
#pragma unroll
            for (int r = 0; r < 4; r++) {
                const int mrow = quad * 4 + r;
                v[r] = bf2f(s.pst[mrow][n]);
            }
            gzx[jt2][g] = v;
        }
    }
    float hreg[2][4];
#pragma unroll
    for (int jt2 = 0; jt2 < 2; jt2++) {
        const int hcol = jb + jt2 * 16 + c;
#pragma unroll
        for (int r = 0; r < 4; r++) {
            const int mrow = quad * 4 + r;
            float hv = bf2f(s.pst[mrow][GN + hcol]);
            hreg[jt2][r] = hv;
            s.h[1][mrow][hcol] = f2bf(hv);
        }
    }
    // ext staging covers ALL TT steps regardless of NSTEPS — keeps the
    // probe's prologue byte-identical to the real kernel's.
    if (tid < TT * GRU_ROWS) {
        const int t = tid >> 4, row = tid & (GRU_ROWS - 1);
        float a0v, a1v;
        if (t == 0) { a0v = s.a0[row][0]; a1v = s.a0[row][1]; }
        else {
            const float* fp = fut + ((size_t)(t - 1) * BN + rows0 + row) * 6 + 2;
            a0v = fp[0]; a1v = fp[1];
        }
        int jj = 0;
#pragma unroll
        for (int q = 1; q < NSG; q++) if (upd[q] <= t) jj = q;
        s.ext[t][row][0] = f2bf(a0v);
        s.ext[t][row][1] = f2bf(a1v);
        s.ext[t][row][2] = f2bf(s.sgf[jj][row][0]);
        s.ext[t][row][3] = f2bf(s.sgf[jj][row][1]);
    }
    __syncthreads();

    // ---------- T loop: 1 lgkm-barrier per step ----------
    for (int t = 0; t < NSTEPS; t++) {
        const int bi = (t & 1) ^ 1;   // holds h_{t-1}
        const int bo = t & 1;

        floatx4 acc[2][3];
#pragma unroll
        for (int jt2 = 0; jt2 < 2; jt2++) {
            acc[jt2][0] = gzx[jt2][0];
            acc[jt2][1] = gzx[jt2][1];
            floatx4 bb; bb[0] = bb[1] = bb[2] = bb[3] = bhh2[jt2];
            acc[jt2][2] = bb;
        }
        floatx4 acch = floatx4{0.f, 0.f, 0.f, 0.f};   // heads(t-1), wave 3
#pragma unroll
        for (int kc = 0; kc < 4; kc++) {
            short8 am = *(const short8*)(&s.h[bi][c][kc * 32 + quad * 8]);
#pragma unroll
            for (int jt2 = 0; jt2 < 2; jt2++)
#pragma unroll
                for (int g = 0; g < 3; g++)
                    acc[jt2][g] = __builtin_amdgcn_mfma_f32_16x16x32_bf16(
                        am, Wb[jt2][g][kc], acc[jt2][g], 0, 0, 0);
            if (wav == 3)
                acch = __builtin_amdgcn_mfma_f32_16x16x32_bf16(
                    am, mwb[kc], acch, 0, 0, 0);
        }
        {
            short8 am4 = {0, 0, 0, 0, 0, 0, 0, 0};
            if (quad == 0) {
                short4_t e = *(const short4_t*)(&s.ext[t][c][0]);
                am4[0] = e[0]; am4[1] = e[1]; am4[2] = e[2]; am4[3] = e[3];
            }
#pragma unroll
            for (int jt2 = 0; jt2 < 2; jt2++)
#pragma unroll
                for (int g = 0; g < 2; g++)
                    acc[jt2][g] = __builtin_amdgcn_mfma_f32_16x16x32_bf16(
                        am4, Wb4[jt2][g], acc[jt2][g], 0, 0, 0);
        }

        // heads(t-1) epilogue: wave 3, lanes c<4 (sel=c), rows quad*4+r
        if (wav == 3 && c < 4 && t > 0) {
#pragma unroll
            for (int r = 0; r < 4; r++) {
                const int row = quad * 4 + r;
                const float v = acch[r] + hbias;
                const size_t g = ((size_t)(t - 1) * BN + rows0 + row) * 2;
                if (c < 2) out[g + c] = v;
                else out[TB2 + g + (c - 2)] = __expf(0.5f * v);
            }
        }

        // gates + h update -> buf bo
#pragma unroll
        for (int r = 0; r < 4; r++) {
            const int mrow = quad * 4 + r;
            short4_t e4 = *(const short4_t*)(&s.ext[t][mrow][0]);
            float a0v = bfraw2f((unsigned short)e4[0]);
            float a1v = bfraw2f((unsigned short)e4[1]);
            float s0v = bfraw2f((unsigned short)e4[2]);
            float s1v = bfraw2f((unsigned short)e4[3]);
#pragma unroll
            for (int jt2 = 0; jt2 < 2; jt2++) {
                float rr = sigm(acc[jt2][0][r]);
                float zg = sigm(acc[jt2][1][r]);
                float tn = a0v * Wa2[jt2][0] + a1v * Wa2[jt2][1]
                         + s0v * Ws2[jt2][0] + s1v * Ws2[jt2][1];
                float narg = gzx[jt2][2][r] + tn + rr * acc[jt2][2][r];
                float nn = tanh_f(narg);
                float hv = nn + zg * (hreg[jt2][r] - nn);
                hreg[jt2][r] = hv;
                s.h[bo][mrow][jb + jt2 * 16 + c] = f2bf(hv);
            }
        }
        barrier_lgkm();
    }

    // heads(NSTEPS-1): 4-MFMA tail on wave 3 reading the final h buffer
    if (wav == 3) {
        const int bf = (NSTEPS - 1) & 1;
        floatx4 acch = floatx4{0.f, 0.f, 0.f, 0.f};
#pragma unroll
        for (int kc = 0; kc < 4; kc++) {
            short8 am = *(const short8*)(&s.h[bf][c][kc * 32 + quad * 8]);
            acch = __builtin_amdgcn_mfma_f32_16x16x32_bf16(
                am, mwb[kc], acch, 0, 0, 0);
        }
        if (c < 4) {
#pragma unroll
            for (int r = 0; r < 4; r++) {
                const int row = quad * 4 + r;
                const float v = acch[r] + hbias;
                const size_t g = ((size_t)(NSTEPS - 1) * BN + rows0 + row) * 2;
                if (c < 2) out[g + c] = v;
                else out[TB2 + g + (c - 2)] = __expf(0.5f * v);
            }
        }
    }
}

extern "C" void kernel_launch(void* const* d_in, const int* in_sizes, int n_in,
                              void* d_out, int out_size, void* d_ws, size_t ws_size,
                              hipStream_t stream) {
    const float* lst  = (const float*)d_in[0];
    const float* lpos = (const float*)d_in[1];
    const float* enc  = (const float*)d_in[2];
    const float* zz   = (const float*)d_in[3];
    const float* sg   = (const float*)d_in[4];
    const float* fut  = (const float*)d_in[5];
    const int*   upd  = (const int*)d_in[6];
    const float* Wdec = (const float*)d_in[7];
    const float* bdec = (const float*)d_in[8];
    const float* Wtv  = (const float*)d_in[9];
    const float* btv  = (const float*)d_in[10];
    const float* Wih  = (const float*)d_in[11];
    const float* bih  = (const float*)d_in[12];
    const float* Whh  = (const float*)d_in[13];
    const float* bhh  = (const float*)d_in[14];
    const float* Wmu  = (const float*)d_in[15];
    const float* bmu  = (const float*)d_in[16];
    const float* Wstd = (const float*)d_in[17];
    const float* bstd = (const float*)d_in[18];
    const float* Wsg  = (const float*)d_in[19];
    const float* bsg  = (const float*)d_in[20];
    float* out = (float*)d_out;

    bf16* P = (bf16*)d_ws;   // 16.78 MB; ws has been >= this all session
    k_gemm<<<512, 512, 0, stream>>>(enc, zz, Wih, Wdec, bih, bhh, bdec, P);
    k_gru<TT><<<BN / GRU_ROWS, 256, 0, stream>>>(
        lst, lpos, sg, fut, upd, Wtv, btv, Wih, Whh, bhh,
        Wmu, bmu, Wstd, bstd, Wsg, bsg, P, out);
    // SLOPE PROBE: identical prologue + 2 steps, output -> ws scratch (the P
    // region is dead after the real k_gru; probe reads possibly-clobbered P,
    // which only affects its garbage output, not timing). Runs after the real
    // kernel on the same stream. per-step=(dur12-dur2)/10; prologue=dur2-2*step.
    k_gru<2><<<BN / GRU_ROWS, 256, 0, stream>>>(
        lst, lpos, sg, fut, upd, Wtv, btv, Wih, Whh, bhh,
        Wmu, bmu, Wstd, bstd, Wsg, bsg, P, (float*)d_ws);
}

// Round 9
// 229.976 us; speedup vs baseline: 1.3055x; 1.3055x over previous
//
#include <hip/hip_runtime.h>
#include <hip/hip_bf16.h>

#define BN 16384
#define TT 12
#define MLP 1024
#define ZD 32
#define HD 128
#define KD 1056          // MLP+ZD
#define GN 384           // 3*H
#define WIH_LD 1060      // MLP+ZD+2*NPRED
#define NSG 4
#define DTC 1.6f
#define PLD 512          // P leading dim: [gates_zx(384) | h0(128)], biases baked in
#define SLD 40           // GEMM LDS tile row stride (bf16): 80B -> <=2-way banks
#define GRU_ROWS 16     // rows per k_gru block (256 threads, 4 waves)

typedef __attribute__((ext_vector_type(8))) short short8;
typedef __attribute__((ext_vector_type(4))) short short4_t;
typedef __attribute__((ext_vector_type(4))) float floatx4;
typedef __hip_bfloat16 bf16;

__device__ __forceinline__ float bf2f(bf16 v) { return __bfloat162float(v); }
__device__ __forceinline__ bf16 f2bf(float v) { return __float2bfloat16(v); }
__device__ __forceinline__ short bfbits(float x) {
    bf16 t = __float2bfloat16(x);
    return __builtin_bit_cast(short, t);
}
__device__ __forceinline__ float bfraw2f(unsigned short u) {
    return __uint_as_float(((unsigned int)u) << 16);
}
// rcp-based gates: saves div sequence; |err| ~1ulp of rcp, fine vs 3.4e-2 thr
__device__ __forceinline__ float sigm(float x) {
    return __builtin_amdgcn_rcpf(1.0f + __expf(-x));
}
__device__ __forceinline__ float tanh_f(float x) {
    return 1.0f - 2.0f * __builtin_amdgcn_rcpf(1.0f + __expf(2.0f * x));
}
__device__ __forceinline__ short8 pack8(floatx4 a, floatx4 b) {
    short8 v;
    v[0]=bfbits(a[0]); v[1]=bfbits(a[1]); v[2]=bfbits(a[2]); v[3]=bfbits(a[3]);
    v[4]=bfbits(b[0]); v[5]=bfbits(b[1]); v[6]=bfbits(b[2]); v[7]=bfbits(b[3]);
    return v;
}
__device__ __forceinline__ short8 ld8f(const float* q) {
    return pack8(*(const floatx4*)q, *(const floatx4*)(q + 4));
}
// barrier that waits LDS ops only — leaves global loads/stores in flight
__device__ __forceinline__ void barrier_lgkm() {
    asm volatile("s_waitcnt lgkmcnt(0)\n\ts_barrier" ::: "memory");
}

// ---------------------------------------------------------------------------
// k_prep: pre-swizzle Whh -> Wsw (bf16, per-lane fragment order).
// Round-8 slope probe: k_gru prologue = ~36 us of the 86 us dispatch; its
// mass is the 24x ld8f Whh gather (64 scattered 32B slivers per wave-load,
// 2-4x line over-fetch + ~400 pack-VALU insts) x 1024 blocks. Doing the
// swizzle ONCE here turns the per-block gather into 24 coalesced 1KB
// wave-loads of an L2-resident 98KB buffer.
// Fragment id f = ((wav*2+jt2)*3+g)*4+kc; lane l holds Whh[n][kcol..kcol+7]
// with n = g*128+wav*32+jt2*16+(l&15), kcol = kc*32+(l>>4)*8.
// ---------------------------------------------------------------------------
__global__ __launch_bounds__(64) void k_prep(
    const float* __restrict__ Whh, bf16* __restrict__ Wsw)
{
    const int f = blockIdx.x;      // 0..95
    const int l = threadIdx.x;     // 0..63
    const int kc = f & 3;
    const int g3 = f >> 2;         // (wav*2+jt2)*3+g
    const int g = g3 % 3;
    const int wj = g3 / 3;         // wav*2+jt2
    const int jt2 = wj & 1;
    const int wav = wj >> 1;
    const int n = g * 128 + wav * 32 + jt2 * 16 + (l & 15);
    const int kcol = kc * 32 + (l >> 4) * 8;
    *(short8*)&Wsw[(size_t)(f * 64 + l) * 8] = ld8f(Whh + (size_t)n * HD + kcol);
}

// ---------------------------------------------------------------------------
// k_gemm — unchanged from round 7 (A-reuse swizzle kept; preserves m%8).
// ---------------------------------------------------------------------------
__global__ __launch_bounds__(512, 4) void k_gemm(
    const float* __restrict__ enc, const float* __restrict__ zz,
    const float* __restrict__ Wih, const float* __restrict__ Wdec,
    const float* __restrict__ bih, const float* __restrict__ bhh,
    const float* __restrict__ bdec,
    bf16* __restrict__ P)
{
    __shared__ __align__(16) bf16 sA[2][128 * SLD];
    __shared__ __align__(16) bf16 sB[2][128 * SLD];
    const int tid = threadIdx.x;
    const int lane = tid & 63;
    const int wav = tid >> 6;
    const int wm2 = wav >> 2;         // 0..1
    const int wn2 = wav & 3;          // 0..3
    const int c = lane & 15;
    const int quad = lane >> 4;
    const int d = blockIdx.x;         // 0..511
    const int xcd = d & 7;
    const int slot = d >> 3;          // 0..63
    const int m0 = ((slot >> 2) * 8 + xcd) * 128;
    const int n0 = (slot & 3) * 128;

    const int srow = tid >> 2;        // 0..127
    const int scq = (tid & 3) * 8;    // 0/8/16/24
    const int nn = n0 + srow;
    const float* arow = enc + (size_t)(m0 + srow) * MLP + scq;
    const float* zrow = zz + (size_t)(m0 + srow) * ZD + scq;
    const float* brow = (nn < GN) ? Wih + (size_t)nn * WIH_LD + scq
                                  : Wdec + (size_t)(nn - GN) * KD + scq;

    floatx4 pa[2][2], pb[2][2];
#pragma unroll
    for (int s0 = 0; s0 < 2; s0++) {
        const float* qa = arow + s0 * 32;
        const float* qb = brow + s0 * 32;
        pa[s0][0] = *(const floatx4*)qa; pa[s0][1] = *(const floatx4*)(qa + 4);
        pb[s0][0] = *(const floatx4*)qb; pb[s0][1] = *(const floatx4*)(qb + 4);
    }

    // per-thread output-column biases (2 cols), L2-hot scalar loads, once
    float bias[2];
#pragma unroll
    for (int j = 0; j < 2; j++) {
        const int n = n0 + wn2 * 32 + j * 16 + c;
        bias[j] = (n < GN) ? (bih[n] + (n < 256 ? bhh[n] : 0.0f)) : bdec[n - GN];
    }

    floatx4 acc[4][2];
#pragma unroll
    for (int i = 0; i < 4; i++)
#pragma unroll
        for (int j = 0; j < 2; j++) acc[i][j] = floatx4{0.f, 0.f, 0.f, 0.f};

    for (int kc = 0; kc < 33; kc++) {
        const int sl = kc & 1;
        *(short8*)&sA[sl][srow * SLD + scq] = pack8(pa[sl][0], pa[sl][1]);
        *(short8*)&sB[sl][srow * SLD + scq] = pack8(pb[sl][0], pb[sl][1]);
        if (kc + 2 < 33) {
            const int k2 = (kc + 2) * 32;
            const float* qa = (kc + 2 < 32) ? arow + k2 : zrow;
            const float* qb = brow + k2;
            pa[sl][0] = *(const floatx4*)qa; pa[sl][1] = *(const floatx4*)(qa + 4);
            pb[sl][0] = *(const floatx4*)qb; pb[sl][1] = *(const floatx4*)(qb + 4);
        }
        barrier_lgkm();
        short8 a[4], b[2];
#pragma unroll
        for (int i = 0; i < 4; i++)
            a[i] = *(const short8*)&sA[sl][(wm2 * 64 + i * 16 + c) * SLD + quad * 8];
#pragma unroll
        for (int j = 0; j < 2; j++)
            b[j] = *(const short8*)&sB[sl][(wn2 * 32 + j * 16 + c) * SLD + quad * 8];
#pragma unroll
        for (int i = 0; i < 4; i++)
#pragma unroll
            for (int j = 0; j < 2; j++)
                acc[i][j] = __builtin_amdgcn_mfma_f32_16x16x32_bf16(
                    a[i], b[j], acc[i][j], 0, 0, 0);
    }
#pragma unroll
    for (int i = 0; i < 4; i++)
#pragma unroll
        for (int j = 0; j < 2; j++)
#pragma unroll
            for (int r = 0; r < 4; r++)
                P[(size_t)(m0 + wm2 * 64 + i * 16 + quad * 4 + r) * PLD
                  + n0 + wn2 * 32 + j * 16 + c] = f2bf(acc[i][j][r] + bias[j]);
}

// ---------------------------------------------------------------------------
// GRU kernel. Round-7 structure; Whh fragments now loaded from pre-swizzled
// Wsw (24 coalesced short8 wave-loads, L2-hot) instead of the scattered
// ld8f gather (round-8 probe: prologue was ~36 us of 86; gather was its mass).
// __launch_bounds__ 2nd arg MUST stay <=2 (round-1: (256,4) spilled Whh).
// ---------------------------------------------------------------------------
struct SMem {
    bf16 pst[GRU_ROWS][520];    // staged P-tile (+8 pad)
    bf16 h[2][GRU_ROWS][136];   // 272B rows: 2-way banks (free) for b128 reads
    bf16 ext[TT][GRU_ROWS][4];  // per-step (a0,a1,sg0,sg1)
    float sgf[NSG][GRU_ROWS][2];
    float a0[GRU_ROWS][2];
};

__global__ __launch_bounds__(256, 2) void k_gru(
    const float* __restrict__ lst, const float* __restrict__ lpos,
    const float* __restrict__ sg, const float* __restrict__ fut,
    const int* __restrict__ updp,
    const float* __restrict__ Wtv, const float* __restrict__ btv,
    const float* __restrict__ Wih,
    const float* __restrict__ bhh,
    const float* __restrict__ Wmu, const float* __restrict__ bmu,
    const float* __restrict__ Wstd, const float* __restrict__ bstd,
    const float* __restrict__ Wsg, const float* __restrict__ bsg,
    const bf16* __restrict__ P, const bf16* __restrict__ Wsw,
    float* __restrict__ out)
{
    __shared__ __align__(16) SMem s;
    const int tid = threadIdx.x;
    const int lane = tid & 63;
    const int wav = tid >> 6;         // 0..3
    const int c = lane & 15;
    const int quad = lane >> 4;
    // XCD-affinity block swizzle (bijective; floor(b/8) === d mod 8)
    const int d = blockIdx.x;
    const int b = 8 * (d & 7) + 64 * (d >> 6) + ((d >> 3) & 7);
    const int rows0 = b * GRU_ROWS;
    const int jb = wav * 32;
    const size_t TB2 = (size_t)TT * BN * 2;

    // ---------- stage P-tile: 4 coalesced 16B loads/thread ----------
#pragma unroll
    for (int it = 0; it < 4; it++) {
        const int idx = it * 256 + tid;      // 0..1023 chunks of 8 bf16
        const int row = idx >> 6;            // 64 chunks per 512-col row
        const int col8 = idx & 63;
        *(short8*)&s.pst[row][col8 * 8] =
            *(const short8*)&P[(size_t)(rows0 + row) * PLD + col8 * 8];
    }

    // ---------- Whh fragments from Wsw: 24 coalesced short8 loads ----------
    short8 Wb[2][3][4];
#pragma unroll
    for (int jt2 = 0; jt2 < 2; jt2++)
#pragma unroll
        for (int g = 0; g < 3; g++)
#pragma unroll
            for (int kc = 0; kc < 4; kc++) {
                const int f = ((wav * 2 + jt2) * 3 + g) * 4 + kc;
                Wb[jt2][g][kc] = *(const short8*)&Wsw[(size_t)(f * 64 + lane) * 8];
            }

    // ---------- prologue misc ----------
    if (tid < GRU_ROWS) {
        const int row = rows0 + tid;
        for (int pp = 0; pp < 2; pp++) {
            float sum = btv[pp];
            for (int f = 0; f < 6; f++)
                sum += lst[(size_t)row * 6 + f] * Wtv[pp * 6 + f];
            s.a0[tid][pp] = sum;
        }
        float px = lpos[(size_t)row * 2];
        float py = lpos[(size_t)row * 2 + 1];
        float prevx = 0.f, prevy = 0.f;
        for (int j = 0; j < NSG; j++) {
            float rx = (sg[((size_t)row * NSG + j) * 2] - px) * 0.01f;
            float ry = (sg[((size_t)row * NSG + j) * 2 + 1] - py) * 0.01f;
            float vx = (rx - prevx) * (1.0f / DTC), vy = (ry - prevy) * (1.0f / DTC);
            prevx = rx; prevy = ry;
            float st4[4] = {rx, ry, vx, vy};
            for (int pp = 0; pp < 2; pp++) {
                float sum = bsg[pp];
                for (int f = 0; f < 4; f++) sum += st4[f] * Wsg[pp * 4 + f];
                s.sgf[j][tid][pp] = sum;
            }
        }
    }
    int upd[4];
#pragma unroll
    for (int i = 0; i < 4; i++) upd[i] = updp[i];

    // small per-column scalars (kept as direct loads; ~10 scalars/thread)
    short8 Wb4[2][2];
    float Wa2[2][2], Ws2[2][2], bhh2[2];
#pragma unroll
    for (int jt2 = 0; jt2 < 2; jt2++) {
#pragma unroll
        for (int g = 0; g < 2; g++) {
            const int n = g * 128 + jb + jt2 * 16 + c;
            short8 v = {0, 0, 0, 0, 0, 0, 0, 0};
            if (quad == 0) {
                const float* q = Wih + (size_t)n * WIH_LD + KD;
                v[0] = bfbits(q[0]); v[1] = bfbits(q[1]);
                v[2] = bfbits(q[2]); v[3] = bfbits(q[3]);
            }
            Wb4[jt2][g] = v;
        }
        const int n2 = 256 + jb + jt2 * 16 + c;
        const float* q2 = Wih + (size_t)n2 * WIH_LD + KD;
        Wa2[jt2][0] = q2[0]; Wa2[jt2][1] = q2[1];
        Ws2[jt2][0] = q2[2]; Ws2[jt2][1] = q2[3];
        bhh2[jt2] = bhh[n2];
    }

    // heads B-fragments: muw as bf16, B-col = sel (c<4), k = kc*32+quad*8.
    short8 mwb[4];
    float hbias = 0.0f;
#pragma unroll
    for (int kc = 0; kc < 4; kc++) {
        short8 v = {0, 0, 0, 0, 0, 0, 0, 0};
        if (c < 4) {
            const float* q = (c < 2 ? Wmu + (size_t)c * HD
                                    : Wstd + (size_t)(c - 2) * HD)
                             + kc * 32 + quad * 8;
            v = ld8f(q);
        }
        mwb[kc] = v;
    }
    if (c < 4) hbias = (c < 2) ? bmu[c] : bstd[c - 2];

    __syncthreads();   // pst + sgf/a0 ready

    // ---------- P1: consume staged P (biases baked); h0 -> buf 1; ext ----------
    floatx4 gzx[2][3];
#pragma unroll
    for (int jt2 = 0; jt2 < 2; jt2++) {
#pragma unroll
        for (int g = 0; g < 3; g++) {
            const int n = g * 128 + jb + jt2 * 16 + c;
            floatx4 v;
#pragma unroll
            for (int r = 0; r < 4; r++) {
                const int mrow = quad * 4 + r;
                v[r] = bf2f(s.pst[mrow][n]);
            }
            gzx[jt2][g] = v;
        }
    }
    float hreg[2][4];
#pragma unroll
    for (int jt2 = 0; jt2 < 2; jt2++) {
        const int hcol = jb + jt2 * 16 + c;
#pragma unroll
        for (int r = 0; r < 4; r++) {
            const int mrow = quad * 4 + r;
            float hv = bf2f(s.pst[mrow][GN + hcol]);
            hreg[jt2][r] = hv;
            s.h[1][mrow][hcol] = f2bf(hv);
        }
    }
    if (tid < TT * GRU_ROWS) {
        const int t = tid >> 4, row = tid & (GRU_ROWS - 1);
        float a0v, a1v;
        if (t == 0) { a0v = s.a0[row][0]; a1v = s.a0[row][1]; }
        else {
            const float* fp = fut + ((size_t)(t - 1) * BN + rows0 + row) * 6 + 2;
            a0v = fp[0]; a1v = fp[1];
        }
        int jj = 0;
#pragma unroll
        for (int q = 1; q < NSG; q++) if (upd[q] <= t) jj = q;
        s.ext[t][row][0] = f2bf(a0v);
        s.ext[t][row][1] = f2bf(a1v);
        s.ext[t][row][2] = f2bf(s.sgf[jj][row][0]);
        s.ext[t][row][3] = f2bf(s.sgf[jj][row][1]);
    }
    __syncthreads();

    // ---------- T loop: 1 lgkm-barrier per step ----------
    for (int t = 0; t < TT; t++) {
        const int bi = (t & 1) ^ 1;   // holds h_{t-1}
        const int bo = t & 1;

        floatx4 acc[2][3];
#pragma unroll
        for (int jt2 = 0; jt2 < 2; jt2++) {
            acc[jt2][0] = gzx[jt2][0];
            acc[jt2][1] = gzx[jt2][1];
            floatx4 bb; bb[0] = bb[1] = bb[2] = bb[3] = bhh2[jt2];
            acc[jt2][2] = bb;
        }
        floatx4 acch = floatx4{0.f, 0.f, 0.f, 0.f};   // heads(t-1), wave 3
#pragma unroll
        for (int kc = 0; kc < 4; kc++) {
            short8 am = *(const short8*)(&s.h[bi][c][kc * 32 + quad * 8]);
#pragma unroll
            for (int jt2 = 0; jt2 < 2; jt2++)
#pragma unroll
                for (int g = 0; g < 3; g++)
                    acc[jt2][g] = __builtin_amdgcn_mfma_f32_16x16x32_bf16(
                        am, Wb[jt2][g][kc], acc[jt2][g], 0, 0, 0);
            if (wav == 3)
                acch = __builtin_amdgcn_mfma_f32_16x16x32_bf16(
                    am, mwb[kc], acch, 0, 0, 0);
        }
        {
            short8 am4 = {0, 0, 0, 0, 0, 0, 0, 0};
            if (quad == 0) {
                short4_t e = *(const short4_t*)(&s.ext[t][c][0]);
                am4[0] = e[0]; am4[1] = e[1]; am4[2] = e[2]; am4[3] = e[3];
            }
#pragma unroll
            for (int jt2 = 0; jt2 < 2; jt2++)
#pragma unroll
                for (int g = 0; g < 2; g++)
                    acc[jt2][g] = __builtin_amdgcn_mfma_f32_16x16x32_bf16(
                        am4, Wb4[jt2][g], acc[jt2][g], 0, 0, 0);
        }

        // heads(t-1) epilogue: wave 3, lanes c<4 (sel=c), rows quad*4+r
        if (wav == 3 && c < 4 && t > 0) {
#pragma unroll
            for (int r = 0; r < 4; r++) {
                const int row = quad * 4 + r;
                const float v = acch[r] + hbias;
                const size_t g = ((size_t)(t - 1) * BN + rows0 + row) * 2;
                if (c < 2) out[g + c] = v;
                else out[TB2 + g + (c - 2)] = __expf(0.5f * v);
            }
        }

        // gates + h update -> buf bo
#pragma unroll
        for (int r = 0; r < 4; r++) {
            const int mrow = quad * 4 + r;
            short4_t e4 = *(const short4_t*)(&s.ext[t][mrow][0]);
            float a0v = bfraw2f((unsigned short)e4[0]);
            float a1v = bfraw2f((unsigned short)e4[1]);
            float s0v = bfraw2f((unsigned short)e4[2]);
            float s1v = bfraw2f((unsigned short)e4[3]);
#pragma unroll
            for (int jt2 = 0; jt2 < 2; jt2++) {
                float rr = sigm(acc[jt2][0][r]);
                float zg = sigm(acc[jt2][1][r]);
                float tn = a0v * Wa2[jt2][0] + a1v * Wa2[jt2][1]
                         + s0v * Ws2[jt2][0] + s1v * Ws2[jt2][1];
                float narg = gzx[jt2][2][r] + tn + rr * acc[jt2][2][r];
                float nn = tanh_f(narg);
                float hv = nn + zg * (hreg[jt2][r] - nn);
                hreg[jt2][r] = hv;
                s.h[bo][mrow][jb + jt2 * 16 + c] = f2bf(hv);
            }
        }
        barrier_lgkm();
    }

    // heads(TT-1): 4-MFMA tail on wave 3 reading the final h buffer
    if (wav == 3) {
        const int bf = (TT - 1) & 1;
        floatx4 acch = floatx4{0.f, 0.f, 0.f, 0.f};
#pragma unroll
        for (int kc = 0; kc < 4; kc++) {
            short8 am = *(const short8*)(&s.h[bf][c][kc * 32 + quad * 8]);
            acch = __builtin_amdgcn_mfma_f32_16x16x32_bf16(
                am, mwb[kc], acch, 0, 0, 0);
        }
        if (c < 4) {
#pragma unroll
            for (int r = 0; r < 4; r++) {
                const int row = quad * 4 + r;
                const float v = acch[r] + hbias;
                const size_t g = ((size_t)(TT - 1) * BN + rows0 + row) * 2;
                if (c < 2) out[g + c] = v;
                else out[TB2 + g + (c - 2)] = __expf(0.5f * v);
            }
        }
    }
}

extern "C" void kernel_launch(void* const* d_in, const int* in_sizes, int n_in,
                              void* d_out, int out_size, void* d_ws, size_t ws_size,
                              hipStream_t stream) {
    const float* lst  = (const float*)d_in[0];
    const float* lpos = (const float*)d_in[1];
    const float* enc  = (const float*)d_in[2];
    const float* zz   = (const float*)d_in[3];
    const float* sg   = (const float*)d_in[4];
    const float* fut  = (const float*)d_in[5];
    const int*   upd  = (const int*)d_in[6];
    const float* Wdec = (const float*)d_in[7];
    const float* bdec = (const float*)d_in[8];
    const float* Wtv  = (const float*)d_in[9];
    const float* btv  = (const float*)d_in[10];
    const float* Wih  = (const float*)d_in[11];
    const float* bih  = (const float*)d_in[12];
    const float* Whh  = (const float*)d_in[13];
    const float* bhh  = (const float*)d_in[14];
    const float* Wmu  = (const float*)d_in[15];
    const float* bmu  = (const float*)d_in[16];
    const float* Wstd = (const float*)d_in[17];
    const float* bstd = (const float*)d_in[18];
    const float* Wsg  = (const float*)d_in[19];
    const float* bsg  = (const float*)d_in[20];
    float* out = (float*)d_out;

    bf16* P = (bf16*)d_ws;                               // 16.78 MB
    bf16* Wsw = (bf16*)((char*)d_ws + (size_t)BN * PLD * sizeof(bf16)); // +96 KB
    k_prep<<<96, 64, 0, stream>>>(Whh, Wsw);
    k_gemm<<<512, 512, 0, stream>>>(enc, zz, Wih, Wdec, bih, bhh, bdec, P);
    k_gru<<<BN / GRU_ROWS, 256, 0, stream>>>(
        lst, lpos, sg, fut, upd, Wtv, btv, Wih, bhh,
        Wmu, bmu, Wstd, bstd, Wsg, bsg, P, Wsw, out);
}